// Round 10
// baseline (20623.509 us; speedup 1.0000x reference)
//
#include <hip/hip_runtime.h>
#include <cstdint>
#include <cstddef>

#define NB 32
#define NT 2048
#define ND 256
#define NH 256
#define NG 1024   // 4*H
#define ROWS 16   // bt-rows per block in zx_kernel

#define TPB 512             // 8 waves = 2/EU, 1 block/CU (LDS-forced)
#define KL  64              // k-values with weights in LDS (8 uint4 rows = 128 KB)
#define NQ  ((ND - KL) / 2) // 96 f16 packs per column in regs (x2 cols)

typedef _Float16 h2_t __attribute__((ext_vector_type(2)));

__device__ __forceinline__ float sigf(float x) {
    return 1.0f / (1.0f + __expf(-x));
}
__device__ __forceinline__ float tanh_fast(float x) {
    return 2.0f / (1.0f + __expf(-2.0f * x)) - 1.0f;
}

__device__ __forceinline__ h2_t as_h2(uint32_t u) {
    union { uint32_t u; h2_t h; } c; c.u = u; return c.h;
}
__device__ __forceinline__ uint32_t packf16(float a, float b) {
    union { uint32_t u; h2_t h; } c;
    c.h[0] = (_Float16)a; c.h[1] = (_Float16)b;
    return c.u;
}
__device__ __forceinline__ uint32_t f16bits(float a) {
    union { uint32_t u; h2_t h; } c;
    c.h[0] = (_Float16)a; c.h[1] = (_Float16)0.0f;
    return c.u & 0xFFFFu;
}
__device__ __forceinline__ float dot2(uint32_t hpack, uint32_t wpack, float acc) {
    return __builtin_amdgcn_fdot2(as_h2(hpack), as_h2(wpack), acc, false);
}

// ---------------------------------------------------------------------------
// Phase 1: ZX[bt][j] = sum_k X[bt][k] * Wi[k][j] + bias[j]
__global__ __launch_bounds__(256) void zx_kernel(const float* __restrict__ X,
                                                 const float* __restrict__ Wi,
                                                 const float* __restrict__ bias,
                                                 float* __restrict__ ZX) {
    __shared__ float xs[ROWS][ND];
    const int tid = threadIdx.x;
    const size_t row0 = (size_t)blockIdx.x * ROWS;

    const float4* Xv = (const float4*)(X + row0 * ND);
    float4* xsv = (float4*)(&xs[0][0]);
#pragma unroll
    for (int i = 0; i < (ROWS * ND / 4) / 256; ++i)
        xsv[tid + i * 256] = Xv[tid + i * 256];
    __syncthreads();

    const int j0 = tid * 4;
    const float4 bv = *(const float4*)(bias + j0);
    float acc[ROWS][4];
#pragma unroll
    for (int r = 0; r < ROWS; ++r) {
        acc[r][0] = bv.x; acc[r][1] = bv.y; acc[r][2] = bv.z; acc[r][3] = bv.w;
    }

    for (int k = 0; k < ND; ++k) {
        const float4 w = *(const float4*)(Wi + (size_t)k * NG + j0);
#pragma unroll
        for (int r = 0; r < ROWS; ++r) {
            const float x = xs[r][k];
            acc[r][0] = fmaf(x, w.x, acc[r][0]);
            acc[r][1] = fmaf(x, w.y, acc[r][1]);
            acc[r][2] = fmaf(x, w.z, acc[r][2]);
            acc[r][3] = fmaf(x, w.w, acc[r][3]);
        }
    }

#pragma unroll
    for (int r = 0; r < ROWS; ++r) {
        float4 o;
        o.x = acc[r][0]; o.y = acc[r][1]; o.z = acc[r][2]; o.w = acc[r][3];
        *(float4*)(ZX + (row0 + r) * NG + j0) = o;
    }
}

// ---------------------------------------------------------------------------
// Phase 2: persistent-weight recurrence, shfl-merged gates, 1 barrier/step.
// One block per batch, 512 threads (8 waves = 2/EU -> 128 arch + AGPR).
// Wave w, lane l: unit u = 32w + (l&31). Lane half A (l<32) owns columns
// {u, 256+u} = (i,f); half B (l>=32) owns {512+u, 768+u} = (g,o). The four
// gate pre-activations of unit u meet via two __shfl_xor(.,32) -- no zs
// array, gates on all 8 waves. h is double-buffered f16 packs in LDS
// (read buf[t&1], write buf[1-(t&1)]) -> ONE __syncthreads per step.
// Weights: k=0..KL-1 in LDS (128 KB); k=KL..255 as 2x96 pinned packs (R8
// residency scheme: 128 arch VGPR + spill-free AGPR overflow).
__global__
__attribute__((amdgpu_flat_work_group_size(TPB, TPB)))
__attribute__((amdgpu_waves_per_eu(2, 2)))
void rec_pers(const float* __restrict__ ZX,
              const float* __restrict__ Wh,
              const int* __restrict__ lengths,
              float* __restrict__ out)
{
    __shared__ uint4 lw[KL / 8][NG];                      // 128 KB
    __shared__ __align__(16) uint32_t hsbuf[2][NH / 2];   // 2 x 512 B f16 packs

    const int b    = blockIdx.x;
    const int tid  = threadIdx.x;
    const int l    = tid & 63;
    const int w    = tid >> 6;
    const int half = l >> 5;                  // 0: (i,f) lanes, 1: (g,o) lanes
    const int u    = w * 32 + (l & 31);       // hidden unit 0..255
    const int col0 = half * 512 + u;          // i- or g-column
    const int col1 = col0 + 256;              // f- or o-column

    // ---- one-time LDS staging (lane-consecutive cols -> coalesced) ----
#pragma unroll
    for (int r = 0; r < KL / 8; ++r) {
        const int k = 8 * r;
        uint4 p;
        p.x = packf16(Wh[(size_t)(k + 0) * NG + col0], Wh[(size_t)(k + 1) * NG + col0]);
        p.y = packf16(Wh[(size_t)(k + 2) * NG + col0], Wh[(size_t)(k + 3) * NG + col0]);
        p.z = packf16(Wh[(size_t)(k + 4) * NG + col0], Wh[(size_t)(k + 5) * NG + col0]);
        p.w = packf16(Wh[(size_t)(k + 6) * NG + col0], Wh[(size_t)(k + 7) * NG + col0]);
        lw[r][col0] = p;
        p.x = packf16(Wh[(size_t)(k + 0) * NG + col1], Wh[(size_t)(k + 1) * NG + col1]);
        p.y = packf16(Wh[(size_t)(k + 2) * NG + col1], Wh[(size_t)(k + 3) * NG + col1]);
        p.z = packf16(Wh[(size_t)(k + 4) * NG + col1], Wh[(size_t)(k + 5) * NG + col1]);
        p.w = packf16(Wh[(size_t)(k + 6) * NG + col1], Wh[(size_t)(k + 7) * NG + col1]);
        lw[r][col1] = p;
    }

    // ---- register-resident weights, pinned against remat (R8 scheme) ----
    uint32_t wa[NQ], wb[NQ];
#pragma unroll
    for (int q = 0; q < NQ; ++q) {
        const int k = KL + 2 * q;
        uint32_t va = packf16(Wh[(size_t)k * NG + col0], Wh[(size_t)(k + 1) * NG + col0]);
        uint32_t vb = packf16(Wh[(size_t)k * NG + col1], Wh[(size_t)(k + 1) * NG + col1]);
        asm volatile("" : "+v"(va));          // opaque def: no remat
        asm volatile("" : "+v"(vb));
        wa[q] = va;
        wb[q] = vb;
    }

    if (tid < NH / 2) { hsbuf[0][tid] = 0u; hsbuf[1][tid] = 0u; }
    float c = 0.0f, hlast = 0.0f;
    __syncthreads();

    const int len   = lengths[b];
    const int steps = (len < 1) ? 1 : len;    // idx = max(0,len-1) -> idx+1 steps

    for (int t = 0; t < steps; ++t) {
        const int p = t & 1;
        const size_t zrow = ((size_t)b * NT + t) * NG;
        const float zx0 = ZX[zrow + col0];    // early issue, consumed post-dots
        const float zx1 = ZX[zrow + col1];

        float a0 = 0.0f, a1 = 0.0f;           // col0 accums
        float b0 = 0.0f, b1 = 0.0f;           // col1 accums
        const uint32_t* hb = &hsbuf[p][0];

        // k = 0..KL-1: weights from LDS (16 B lane stride = free 2-way)
#pragma unroll
        for (int r = 0; r < KL / 8; ++r) {
            const uint4 h4 = *(const uint4*)(hb + 4 * r);     // broadcast
            const uint4 pa = lw[r][col0];
            const uint4 pb = lw[r][col1];
            a0 = dot2(h4.x, pa.x, a0); a1 = dot2(h4.y, pa.y, a1);
            a0 = dot2(h4.z, pa.z, a0); a1 = dot2(h4.w, pa.w, a1);
            b0 = dot2(h4.x, pb.x, b0); b1 = dot2(h4.y, pb.y, b1);
            b0 = dot2(h4.z, pb.z, b0); b1 = dot2(h4.w, pb.w, b1);
        }

        // k = KL..255: register-resident weights
#pragma unroll
        for (int m = 0; m < NQ / 4; ++m) {
            const uint4 h4 = *(const uint4*)(hb + KL / 2 + 4 * m);  // broadcast
            a0 = dot2(h4.x, wa[4 * m + 0], a0);
            a1 = dot2(h4.y, wa[4 * m + 1], a1);
            a0 = dot2(h4.z, wa[4 * m + 2], a0);
            a1 = dot2(h4.w, wa[4 * m + 3], a1);
            b0 = dot2(h4.x, wb[4 * m + 0], b0);
            b1 = dot2(h4.y, wb[4 * m + 1], b1);
            b0 = dot2(h4.z, wb[4 * m + 2], b0);
            b1 = dot2(h4.w, wb[4 * m + 3], b1);
        }

        const float zsA = zx0 + a0 + a1;      // i (half 0) or g (half 1)
        const float zsB = zx1 + b0 + b1;      // f (half 0) or o (half 1)

        // gate merge: lanes l and l^32 hold (i,f) and (g,o) of the same unit
        const float act0 = half ? tanh_fast(zsA) : sigf(zsA);   // i' or g'
        const float act1 = sigf(zsB);                           // f' or o'
        const float x0 = __shfl_xor(act0, 32);
        const float x1 = __shfl_xor(act1, 32);
        const float iP = half ? x0 : act0;
        const float gP = half ? act0 : x0;
        const float fP = half ? x1 : act1;
        const float oP = half ? act1 : x1;

        c = fP * c + iP * gP;                 // both halves keep identical state
        hlast = oP * tanh_fast(c);

        // pack h to f16 pairs; even lanes of half A write (units 2m, 2m+1)
        const uint32_t hbits = f16bits(hlast);
        const uint32_t nbits = __shfl_xor(hbits, 1);
        if ((l & 33) == 0)
            hsbuf[1 - p][w * 16 + ((l & 31) >> 1)] = hbits | (nbits << 16);

        __syncthreads();                      // new-h buffer visible
    }

    if (half == 0) out[(size_t)b * NH + u] = hlast;
}

// ---------------------------------------------------------------------------
// Fallback recurrence (streams weights; used only if ws can't hold ZX)
__global__ __launch_bounds__(512) void rec_fallback(
    const float* __restrict__ X,
    const float* __restrict__ Wi,
    const float* __restrict__ Wh,
    const float* __restrict__ bias,
    const int* __restrict__ lengths,
    float* __restrict__ out)
{
    __shared__ float hs[NH];
    __shared__ float zs[NG];
    __shared__ float xs[ND];

    const int b   = blockIdx.x;
    const int tid = threadIdx.x;
    const int c0  = tid * 2;

    const int len   = lengths[b];
    const int steps = (len < 1) ? 1 : len;

    float c_state = 0.0f;
    if (tid < NH) hs[tid] = 0.0f;
    const float b0 = bias[c0], b1 = bias[c0 + 1];
    __syncthreads();

    for (int t = 0; t < steps; ++t) {
        float a0 = b0, a1 = b1;
        if (tid < ND) xs[tid] = X[((size_t)b * NT + t) * ND + tid];
        __syncthreads();
#pragma unroll 2
        for (int k = 0; k < ND; k += 4) {
            const float4 xv = *(const float4*)(xs + k);
            const float2 w0 = *(const float2*)(Wi + (size_t)(k + 0) * NG + c0);
            const float2 w1 = *(const float2*)(Wi + (size_t)(k + 1) * NG + c0);
            const float2 w2 = *(const float2*)(Wi + (size_t)(k + 2) * NG + c0);
            const float2 w3 = *(const float2*)(Wi + (size_t)(k + 3) * NG + c0);
            a0 = fmaf(xv.x, w0.x, a0); a1 = fmaf(xv.x, w0.y, a1);
            a0 = fmaf(xv.y, w1.x, a0); a1 = fmaf(xv.y, w1.y, a1);
            a0 = fmaf(xv.z, w2.x, a0); a1 = fmaf(xv.z, w2.y, a1);
            a0 = fmaf(xv.w, w3.x, a0); a1 = fmaf(xv.w, w3.y, a1);
        }
#pragma unroll 2
        for (int k = 0; k < NH; k += 4) {
            const float4 hv = *(const float4*)(hs + k);
            const float2 w0 = *(const float2*)(Wh + (size_t)(k + 0) * NG + c0);
            const float2 w1 = *(const float2*)(Wh + (size_t)(k + 1) * NG + c0);
            const float2 w2 = *(const float2*)(Wh + (size_t)(k + 2) * NG + c0);
            const float2 w3 = *(const float2*)(Wh + (size_t)(k + 3) * NG + c0);
            a0 = fmaf(hv.x, w0.x, a0); a1 = fmaf(hv.x, w0.y, a1);
            a0 = fmaf(hv.y, w1.x, a0); a1 = fmaf(hv.y, w1.y, a1);
            a0 = fmaf(hv.z, w2.x, a0); a1 = fmaf(hv.z, w2.y, a1);
            a0 = fmaf(hv.w, w3.x, a0); a1 = fmaf(hv.w, w3.y, a1);
        }

        float2 zo2; zo2.x = a0; zo2.y = a1;
        *(float2*)(zs + c0) = zo2;
        __syncthreads();

        if (tid < NH) {
            const float iv = zs[tid];
            const float fv = zs[NH + tid];
            const float gv = zs[2 * NH + tid];
            const float ov = zs[3 * NH + tid];
            c_state = sigf(fv) * c_state + sigf(iv) * tanh_fast(gv);
            hs[tid] = sigf(ov) * tanh_fast(c_state);
        }
        __syncthreads();
    }

    if (tid < NH) out[(size_t)b * NH + tid] = hs[tid];
}

extern "C" void kernel_launch(void* const* d_in, const int* in_sizes, int n_in,
                              void* d_out, int out_size, void* d_ws, size_t ws_size,
                              hipStream_t stream) {
    const float* X       = (const float*)d_in[0];
    const int*   lengths = (const int*)d_in[1];
    const float* Wi      = (const float*)d_in[2];
    const float* Wh      = (const float*)d_in[3];
    const float* bias    = (const float*)d_in[4];
    float* out = (float*)d_out;

    const size_t zx_bytes = (size_t)NB * NT * NG * sizeof(float);  // 256 MB
    float* ZX = (float*)d_ws;

    if (ws_size >= zx_bytes) {
        zx_kernel<<<dim3((NB * NT) / ROWS), dim3(256), 0, stream>>>(X, Wi, bias, ZX);
        rec_pers<<<dim3(NB), dim3(TPB), 0, stream>>>(ZX, Wh, lengths, out);
    } else {
        rec_fallback<<<dim3(NB), dim3(512), 0, stream>>>(X, Wi, Wh, bias, lengths, out);
    }
}

// Round 11
// 8545.055 us; speedup vs baseline: 2.4135x; 2.4135x over previous
//
#include <hip/hip_runtime.h>
#include <cstdint>
#include <cstddef>

#define NB 32
#define NT 2048
#define ND 256
#define NH 256
#define NG 1024   // 4*H
#define ROWS 16   // bt-rows per block in zx_kernel

#define TPB 256             // 4 waves = 1/EU -> 512-reg unified budget/thread
#define KL  64              // k-values with weights in LDS (8 uint4 rows = 128 KB)
#define NQ  ((ND - KL) / 2) // 96 f16 packs per gate column in regs (x4 cols)

typedef _Float16 h2_t __attribute__((ext_vector_type(2)));

__device__ __forceinline__ float sigf(float x) {
    return 1.0f / (1.0f + __expf(-x));
}
__device__ __forceinline__ float tanh_fast(float x) {
    return 2.0f / (1.0f + __expf(-2.0f * x)) - 1.0f;
}

__device__ __forceinline__ h2_t as_h2(uint32_t u) {
    union { uint32_t u; h2_t h; } c; c.u = u; return c.h;
}
__device__ __forceinline__ uint32_t packf16(float a, float b) {
    union { uint32_t u; h2_t h; } c;
    c.h[0] = (_Float16)a; c.h[1] = (_Float16)b;
    return c.u;
}
__device__ __forceinline__ uint32_t f16bits(float a) {
    union { uint32_t u; h2_t h; } c;
    c.h[0] = (_Float16)a; c.h[1] = (_Float16)0.0f;
    return c.u & 0xFFFFu;
}
__device__ __forceinline__ float dot2(uint32_t hpack, uint32_t wpack, float acc) {
    return __builtin_amdgcn_fdot2(as_h2(hpack), as_h2(wpack), acc, false);
}

// ---------------------------------------------------------------------------
// Phase 1: ZX[bt][j] = sum_k X[bt][k] * Wi[k][j] + bias[j]
__global__ __launch_bounds__(256) void zx_kernel(const float* __restrict__ X,
                                                 const float* __restrict__ Wi,
                                                 const float* __restrict__ bias,
                                                 float* __restrict__ ZX) {
    __shared__ float xs[ROWS][ND];
    const int tid = threadIdx.x;
    const size_t row0 = (size_t)blockIdx.x * ROWS;

    const float4* Xv = (const float4*)(X + row0 * ND);
    float4* xsv = (float4*)(&xs[0][0]);
#pragma unroll
    for (int i = 0; i < (ROWS * ND / 4) / 256; ++i)
        xsv[tid + i * 256] = Xv[tid + i * 256];
    __syncthreads();

    const int j0 = tid * 4;
    const float4 bv = *(const float4*)(bias + j0);
    float acc[ROWS][4];
#pragma unroll
    for (int r = 0; r < ROWS; ++r) {
        acc[r][0] = bv.x; acc[r][1] = bv.y; acc[r][2] = bv.z; acc[r][3] = bv.w;
    }

    for (int k = 0; k < ND; ++k) {
        const float4 w = *(const float4*)(Wi + (size_t)k * NG + j0);
#pragma unroll
        for (int r = 0; r < ROWS; ++r) {
            const float x = xs[r][k];
            acc[r][0] = fmaf(x, w.x, acc[r][0]);
            acc[r][1] = fmaf(x, w.y, acc[r][1]);
            acc[r][2] = fmaf(x, w.z, acc[r][2]);
            acc[r][3] = fmaf(x, w.w, acc[r][3]);
        }
    }

#pragma unroll
    for (int r = 0; r < ROWS; ++r) {
        float4 o;
        o.x = acc[r][0]; o.y = acc[r][1]; o.z = acc[r][2]; o.w = acc[r][3];
        *(float4*)(ZX + (row0 + r) * NG + j0) = o;
    }
}

// ---------------------------------------------------------------------------
// Phase 2: persistent-weight recurrence, gate-local columns, 1 barrier/step.
// One block per batch, 256 threads (4 waves = 1/EU -> 512-reg budget).
// Thread u owns columns {u, 256+u, 512+u, 768+u} = (i,f,g,o) of unit u:
// gate math is thread-local (no zs exchange). h double-buffered as f16
// packs in LDS: read hbuf[t&1], write hbuf[1-(t&1)], ONE barrier/step.
// Weights: k=0..KL-1 in LDS (128 KB); k=KL..255 as 4x96=384 pinned packs
// (75% of the 512-reg budget -- more RA slack than R8's proven 87%).
__global__
__attribute__((amdgpu_flat_work_group_size(TPB, TPB)))
__attribute__((amdgpu_waves_per_eu(1, 1)))
void rec_pers(const float* __restrict__ ZX,
              const float* __restrict__ Wh,
              const int* __restrict__ lengths,
              float* __restrict__ out)
{
    __shared__ uint4 lw[KL / 8][NG];                      // 128 KB
    __shared__ __align__(16) uint32_t hsbuf[2][NH / 2];   // 2 x 512 B f16 packs

    const int b = blockIdx.x;
    const int u = threadIdx.x;            // hidden unit 0..255
    const int l = u & 63;

    // ---- one-time LDS staging (lane-consecutive cols -> coalesced) ----
#pragma unroll
    for (int r = 0; r < KL / 8; ++r) {
        const int k = 8 * r;
#pragma unroll
        for (int cidx = 0; cidx < 4; ++cidx) {
            const int col = u + cidx * 256;
            uint4 p;
            p.x = packf16(Wh[(size_t)(k + 0) * NG + col], Wh[(size_t)(k + 1) * NG + col]);
            p.y = packf16(Wh[(size_t)(k + 2) * NG + col], Wh[(size_t)(k + 3) * NG + col]);
            p.z = packf16(Wh[(size_t)(k + 4) * NG + col], Wh[(size_t)(k + 5) * NG + col]);
            p.w = packf16(Wh[(size_t)(k + 6) * NG + col], Wh[(size_t)(k + 7) * NG + col]);
            lw[r][col] = p;
        }
    }

    // ---- register-resident weights, pinned against remat (R8 scheme) ----
    uint32_t wi_[NQ], wf_[NQ], wg_[NQ], wo_[NQ];
#pragma unroll
    for (int q = 0; q < NQ; ++q) {
        const int k = KL + 2 * q;
        uint32_t vi = packf16(Wh[(size_t)k * NG + u],       Wh[(size_t)(k + 1) * NG + u]);
        uint32_t vf = packf16(Wh[(size_t)k * NG + u + 256], Wh[(size_t)(k + 1) * NG + u + 256]);
        uint32_t vg = packf16(Wh[(size_t)k * NG + u + 512], Wh[(size_t)(k + 1) * NG + u + 512]);
        uint32_t vo = packf16(Wh[(size_t)k * NG + u + 768], Wh[(size_t)(k + 1) * NG + u + 768]);
        asm volatile("" : "+v"(vi));      // opaque defs: no remat/resink
        asm volatile("" : "+v"(vf));
        asm volatile("" : "+v"(vg));
        asm volatile("" : "+v"(vo));
        wi_[q] = vi; wf_[q] = vf; wg_[q] = vg; wo_[q] = vo;
    }

    if (u < NH / 2) { hsbuf[0][u] = 0u; hsbuf[1][u] = 0u; }
    float c = 0.0f, hlast = 0.0f;
    __syncthreads();

    const int len   = lengths[b];
    const int steps = (len < 1) ? 1 : len;     // idx = max(0,len-1) -> idx+1 steps

    for (int t = 0; t < steps; ++t) {
        const int p = t & 1;
        const size_t zrow = ((size_t)b * NT + t) * NG + u;
        const float zi = ZX[zrow];             // early issue; consumed post-dots
        const float zf = ZX[zrow + 256];
        const float zg = ZX[zrow + 512];
        const float zo = ZX[zrow + 768];

        float i0 = 0.0f, i1 = 0.0f, f0 = 0.0f, f1 = 0.0f;
        float g0 = 0.0f, g1 = 0.0f, o0 = 0.0f, o1 = 0.0f;
        const uint32_t* hb = &hsbuf[p][0];

        // k = 0..KL-1: weights from LDS (16 B lane stride = free 2-way)
#pragma unroll
        for (int r = 0; r < KL / 8; ++r) {
            const uint4 h4 = *(const uint4*)(hb + 4 * r);     // broadcast
            const uint4 pi = lw[r][u];
            const uint4 pf = lw[r][u + 256];
            const uint4 pg = lw[r][u + 512];
            const uint4 po = lw[r][u + 768];
            i0 = dot2(h4.x, pi.x, i0); i1 = dot2(h4.y, pi.y, i1);
            i0 = dot2(h4.z, pi.z, i0); i1 = dot2(h4.w, pi.w, i1);
            f0 = dot2(h4.x, pf.x, f0); f1 = dot2(h4.y, pf.y, f1);
            f0 = dot2(h4.z, pf.z, f0); f1 = dot2(h4.w, pf.w, f1);
            g0 = dot2(h4.x, pg.x, g0); g1 = dot2(h4.y, pg.y, g1);
            g0 = dot2(h4.z, pg.z, g0); g1 = dot2(h4.w, pg.w, g1);
            o0 = dot2(h4.x, po.x, o0); o1 = dot2(h4.y, po.y, o1);
            o0 = dot2(h4.z, po.z, o0); o1 = dot2(h4.w, po.w, o1);
        }

        // k = KL..255: register-resident weights
#pragma unroll
        for (int m = 0; m < NQ / 4; ++m) {
            const uint4 h4 = *(const uint4*)(hb + KL / 2 + 4 * m);  // broadcast
            i0 = dot2(h4.x, wi_[4 * m + 0], i0);
            i1 = dot2(h4.y, wi_[4 * m + 1], i1);
            i0 = dot2(h4.z, wi_[4 * m + 2], i0);
            i1 = dot2(h4.w, wi_[4 * m + 3], i1);
            f0 = dot2(h4.x, wf_[4 * m + 0], f0);
            f1 = dot2(h4.y, wf_[4 * m + 1], f1);
            f0 = dot2(h4.z, wf_[4 * m + 2], f0);
            f1 = dot2(h4.w, wf_[4 * m + 3], f1);
            g0 = dot2(h4.x, wg_[4 * m + 0], g0);
            g1 = dot2(h4.y, wg_[4 * m + 1], g1);
            g0 = dot2(h4.z, wg_[4 * m + 2], g0);
            g1 = dot2(h4.w, wg_[4 * m + 3], g1);
            o0 = dot2(h4.x, wo_[4 * m + 0], o0);
            o1 = dot2(h4.y, wo_[4 * m + 1], o1);
            o0 = dot2(h4.z, wo_[4 * m + 2], o0);
            o1 = dot2(h4.w, wo_[4 * m + 3], o1);
        }

        // gate phase: fully thread-local
        const float iv = zi + i0 + i1;
        const float fv = zf + f0 + f1;
        const float gv = zg + g0 + g1;
        const float ov = zo + o0 + o1;
        c = sigf(fv) * c + sigf(iv) * tanh_fast(gv);
        hlast = sigf(ov) * tanh_fast(c);

        // pack h to f16 pairs: even unit writes pack (u, u+1)
        const uint32_t hbits = f16bits(hlast);
        const uint32_t nbits = __shfl_xor(hbits, 1);
        if ((l & 1) == 0)
            hsbuf[1 - p][u >> 1] = hbits | (nbits << 16);

        __syncthreads();                       // new-h buffer visible
    }

    out[(size_t)b * NH + u] = hlast;
}

// ---------------------------------------------------------------------------
// Fallback recurrence (streams weights; used only if ws can't hold ZX)
__global__ __launch_bounds__(512) void rec_fallback(
    const float* __restrict__ X,
    const float* __restrict__ Wi,
    const float* __restrict__ Wh,
    const float* __restrict__ bias,
    const int* __restrict__ lengths,
    float* __restrict__ out)
{
    __shared__ float hs[NH];
    __shared__ float zs[NG];
    __shared__ float xs[ND];

    const int b   = blockIdx.x;
    const int tid = threadIdx.x;
    const int c0  = tid * 2;

    const int len   = lengths[b];
    const int steps = (len < 1) ? 1 : len;

    float c_state = 0.0f;
    if (tid < NH) hs[tid] = 0.0f;
    const float b0 = bias[c0], b1 = bias[c0 + 1];
    __syncthreads();

    for (int t = 0; t < steps; ++t) {
        float a0 = b0, a1 = b1;
        if (tid < ND) xs[tid] = X[((size_t)b * NT + t) * ND + tid];
        __syncthreads();
#pragma unroll 2
        for (int k = 0; k < ND; k += 4) {
            const float4 xv = *(const float4*)(xs + k);
            const float2 w0 = *(const float2*)(Wi + (size_t)(k + 0) * NG + c0);
            const float2 w1 = *(const float2*)(Wi + (size_t)(k + 1) * NG + c0);
            const float2 w2 = *(const float2*)(Wi + (size_t)(k + 2) * NG + c0);
            const float2 w3 = *(const float2*)(Wi + (size_t)(k + 3) * NG + c0);
            a0 = fmaf(xv.x, w0.x, a0); a1 = fmaf(xv.x, w0.y, a1);
            a0 = fmaf(xv.y, w1.x, a0); a1 = fmaf(xv.y, w1.y, a1);
            a0 = fmaf(xv.z, w2.x, a0); a1 = fmaf(xv.z, w2.y, a1);
            a0 = fmaf(xv.w, w3.x, a0); a1 = fmaf(xv.w, w3.y, a1);
        }
#pragma unroll 2
        for (int k = 0; k < NH; k += 4) {
            const float4 hv = *(const float4*)(hs + k);
            const float2 w0 = *(const float2*)(Wh + (size_t)(k + 0) * NG + c0);
            const float2 w1 = *(const float2*)(Wh + (size_t)(k + 1) * NG + c0);
            const float2 w2 = *(const float2*)(Wh + (size_t)(k + 2) * NG + c0);
            const float2 w3 = *(const float2*)(Wh + (size_t)(k + 3) * NG + c0);
            a0 = fmaf(hv.x, w0.x, a0); a1 = fmaf(hv.x, w0.y, a1);
            a0 = fmaf(hv.y, w1.x, a0); a1 = fmaf(hv.y, w1.y, a1);
            a0 = fmaf(hv.z, w2.x, a0); a1 = fmaf(hv.z, w2.y, a1);
            a0 = fmaf(hv.w, w3.x, a0); a1 = fmaf(hv.w, w3.y, a1);
        }

        float2 zo2; zo2.x = a0; zo2.y = a1;
        *(float2*)(zs + c0) = zo2;
        __syncthreads();

        if (tid < NH) {
            const float iv = zs[tid];
            const float fv = zs[NH + tid];
            const float gv = zs[2 * NH + tid];
            const float ov = zs[3 * NH + tid];
            c_state = sigf(fv) * c_state + sigf(iv) * tanh_fast(gv);
            hs[tid] = sigf(ov) * tanh_fast(c_state);
        }
        __syncthreads();
    }

    if (tid < NH) out[(size_t)b * NH + tid] = hs[tid];
}

extern "C" void kernel_launch(void* const* d_in, const int* in_sizes, int n_in,
                              void* d_out, int out_size, void* d_ws, size_t ws_size,
                              hipStream_t stream) {
    const float* X       = (const float*)d_in[0];
    const int*   lengths = (const int*)d_in[1];
    const float* Wi      = (const float*)d_in[2];
    const float* Wh      = (const float*)d_in[3];
    const float* bias    = (const float*)d_in[4];
    float* out = (float*)d_out;

    const size_t zx_bytes = (size_t)NB * NT * NG * sizeof(float);  // 256 MB
    float* ZX = (float*)d_ws;

    if (ws_size >= zx_bytes) {
        zx_kernel<<<dim3((NB * NT) / ROWS), dim3(256), 0, stream>>>(X, Wi, bias, ZX);
        rec_pers<<<dim3(NB), dim3(TPB), 0, stream>>>(ZX, Wh, lengths, out);
    } else {
        rec_fallback<<<dim3(NB), dim3(512), 0, stream>>>(X, Wi, Wh, bias, lengths, out);
    }
}

// Round 12
// 3134.064 us; speedup vs baseline: 6.5804x; 2.7265x over previous
//
#include <hip/hip_runtime.h>
#include <cstdint>
#include <cstddef>

#define NB 32
#define NT 2048
#define ND 256
#define NH 256
#define NG 1024   // 4*H

#define TPB 512             // rec: 8 waves = 2/EU, 1 block/CU (LDS-forced)
#define KL  64              // k-values with weights in LDS (8 uint4 rows = 128 KB)
#define NQ  ((ND - KL) / 2) // 96 f16 packs per column in regs (x2 cols)

typedef _Float16 h2_t  __attribute__((ext_vector_type(2)));
typedef _Float16 f16x8 __attribute__((ext_vector_type(8)));
typedef float    f32x4 __attribute__((ext_vector_type(4)));

__device__ __forceinline__ float sigf(float x) {
    return 1.0f / (1.0f + __expf(-x));
}
__device__ __forceinline__ float tanh_fast(float x) {
    return 2.0f / (1.0f + __expf(-2.0f * x)) - 1.0f;
}

__device__ __forceinline__ h2_t as_h2(uint32_t u) {
    union { uint32_t u; h2_t h; } c; c.u = u; return c.h;
}
__device__ __forceinline__ uint32_t packf16(float a, float b) {
    union { uint32_t u; h2_t h; } c;
    c.h[0] = (_Float16)a; c.h[1] = (_Float16)b;
    return c.u;
}
__device__ __forceinline__ float dot2(uint32_t hpack, uint32_t wpack, float acc) {
    return __builtin_amdgcn_fdot2(as_h2(hpack), as_h2(wpack), acc, false);
}

// ---------------------------------------------------------------------------
// Phase 1: ZX[bt][j] = sum_k X[bt][k] * Wi[k][j] + bias[j]  via f16 MFMA.
// Grid (1024, 4): block = 64 bt-rows x 256 cols. 256 threads = 4 waves in a
// 2M x 2N grid; per wave 2 M-tiles x 8 N-tiles of 16x16x32. X-tile staged to
// LDS as f16 once (single barrier); B-frags read directly from L2-resident Wi
// (16 consecutive lanes read 16 consecutive f32 = 64B coalesced segments).
// Fragment mapping reused from the R5 kernel that PASSED e2e validation:
//   A: lane l holds A[row=l&15][k=8*(l>>4)+j], j=0..7
//   B: lane l holds B[k=8*(l>>4)+j][col=l&15]
//   D: col=l&15, row=4*(l>>4)+reg
__global__ __launch_bounds__(256) void zx_mfma(const float* __restrict__ X,
                                               const float* __restrict__ Wi,
                                               const float* __restrict__ bias,
                                               float* __restrict__ ZX)
{
    __shared__ _Float16 XL[64][264];               // 33.8 KB (pad 8 -> 2-way free)

    const int t    = threadIdx.x;
    const int mblk = blockIdx.x;
    const int nblk = blockIdx.y;
    const size_t row0 = (size_t)mblk * 64;
    const int n0   = nblk * 256;
    const int l    = t & 63;
    const int w    = t >> 6;
    const int cc   = l & 15;                       // A-row / B-col / D-col class
    const int g    = l >> 4;                       // k-group / D-row class
    const int wm   = (w & 1) * 32;                 // wave M offset
    const int wn   = (w >> 1) * 128;               // wave N offset

    // ---- stage X tile: 64 rows x 256 f32 -> f16 (coalesced float4) ----
    const float4* Xv = (const float4*)(X + row0 * ND);
#pragma unroll
    for (int i = 0; i < 16; ++i) {
        const int q   = i * 256 + t;               // float4 index in tile
        const int row = q >> 6;
        const int c4  = q & 63;
        const float4 v = Xv[q];
        _Float16* dst = &XL[row][c4 * 4];
        dst[0] = (_Float16)v.x; dst[1] = (_Float16)v.y;
        dst[2] = (_Float16)v.z; dst[3] = (_Float16)v.w;
    }
    __syncthreads();

    // ---- accumulators, bias in C operand (D col = cc for all 4 regs) ----
    f32x4 acc[2][8];
#pragma unroll
    for (int nt = 0; nt < 8; ++nt) {
        const float bv = bias[n0 + wn + nt * 16 + cc];
        f32x4 a; a[0] = bv; a[1] = bv; a[2] = bv; a[3] = bv;
        acc[0][nt] = a; acc[1][nt] = a;
    }

#pragma unroll
    for (int kt = 0; kt < 8; ++kt) {
        const f16x8 av0 = *(const f16x8*)&XL[wm +      cc][kt * 32 + 8 * g];
        const f16x8 av1 = *(const f16x8*)&XL[wm + 16 + cc][kt * 32 + 8 * g];
#pragma unroll
        for (int nt = 0; nt < 8; ++nt) {
            const float* wp = Wi + (size_t)(kt * 32 + 8 * g) * NG
                              + n0 + wn + nt * 16 + cc;
            f16x8 bv;
#pragma unroll
            for (int j = 0; j < 8; ++j) bv[j] = (_Float16)wp[(size_t)j * NG];
            acc[0][nt] = __builtin_amdgcn_mfma_f32_16x16x32_f16(av0, bv, acc[0][nt], 0, 0, 0);
            acc[1][nt] = __builtin_amdgcn_mfma_f32_16x16x32_f16(av1, bv, acc[1][nt], 0, 0, 0);
        }
    }

    // ---- write out: D row = 4*g + r, col = cc ----
#pragma unroll
    for (int m = 0; m < 2; ++m)
#pragma unroll
        for (int nt = 0; nt < 8; ++nt)
#pragma unroll
            for (int r = 0; r < 4; ++r) {
                const size_t row = row0 + wm + 16 * m + 4 * g + r;
                ZX[row * NG + n0 + wn + nt * 16 + cc] = acc[m][nt][r];
            }
}

// ---------------------------------------------------------------------------
// Phase 2: persistent-weight recurrence (R8, best measured: 1.45 us/step).
// One block per batch, 512 threads (8 waves = 2/EU). Thread tid owns gate
// columns {tid, tid+512}. Wh packed f16: k=0..KL-1 in LDS (128 KB);
// k=KL..255 as 2x96 packs pinned via opaque asm (no remat -> no spill).
__global__
__attribute__((amdgpu_flat_work_group_size(TPB, TPB)))
__attribute__((amdgpu_waves_per_eu(2, 2)))
void rec_pers(const float* __restrict__ ZX,
              const float* __restrict__ Wh,
              const int* __restrict__ lengths,
              float* __restrict__ out)
{
    __shared__ uint4 lw[KL / 8][NG];               // 128 KB
    __shared__ float zs[NG];                       // 4 KB
    __shared__ __align__(16) _Float16 hs_h[NH];    // 512 B

    const int b   = blockIdx.x;
    const int tid = threadIdx.x;
    const int j0  = tid;
    const int j1  = tid + 512;

    // ---- one-time LDS staging (coalesced over j at fixed k) ----
#pragma unroll
    for (int r = 0; r < KL / 8; ++r) {
        const int k = 8 * r;
        uint4 p;
        p.x = packf16(Wh[(size_t)(k + 0) * NG + j0], Wh[(size_t)(k + 1) * NG + j0]);
        p.y = packf16(Wh[(size_t)(k + 2) * NG + j0], Wh[(size_t)(k + 3) * NG + j0]);
        p.z = packf16(Wh[(size_t)(k + 4) * NG + j0], Wh[(size_t)(k + 5) * NG + j0]);
        p.w = packf16(Wh[(size_t)(k + 6) * NG + j0], Wh[(size_t)(k + 7) * NG + j0]);
        lw[r][j0] = p;
        p.x = packf16(Wh[(size_t)(k + 0) * NG + j1], Wh[(size_t)(k + 1) * NG + j1]);
        p.y = packf16(Wh[(size_t)(k + 2) * NG + j1], Wh[(size_t)(k + 3) * NG + j1]);
        p.z = packf16(Wh[(size_t)(k + 4) * NG + j1], Wh[(size_t)(k + 5) * NG + j1]);
        p.w = packf16(Wh[(size_t)(k + 6) * NG + j1], Wh[(size_t)(k + 7) * NG + j1]);
        lw[r][j1] = p;
    }

    // ---- register-resident weights, pinned against remat ----
    uint32_t wa[NQ], wb[NQ];
#pragma unroll
    for (int q = 0; q < NQ; ++q) {
        const int k = KL + 2 * q;
        uint32_t va = packf16(Wh[(size_t)k * NG + j0], Wh[(size_t)(k + 1) * NG + j0]);
        uint32_t vb = packf16(Wh[(size_t)k * NG + j1], Wh[(size_t)(k + 1) * NG + j1]);
        asm volatile("" : "+v"(va));               // opaque def: no remat
        asm volatile("" : "+v"(vb));
        wa[q] = va;
        wb[q] = vb;
    }

    if (tid < NH) hs_h[tid] = (_Float16)0.0f;
    float c = 0.0f, hlast = 0.0f;
    __syncthreads();

    const int len   = lengths[b];
    const int steps = (len < 1) ? 1 : len;         // idx = max(0,len-1) -> idx+1 steps

    for (int t = 0; t < steps; ++t) {
        // issue early; consumed only at zs write (dot work hides L3/HBM latency)
        const float zx0 = ZX[((size_t)b * NT + t) * NG + j0];
        const float zx1 = ZX[((size_t)b * NT + t) * NG + j1];

        float a0 = 0.0f, a1 = 0.0f;    // col j0
        float b0 = 0.0f, b1 = 0.0f;    // col j1

        // k = 0..KL-1: weights from LDS (16B lane stride = free 2-way)
#pragma unroll
        for (int r = 0; r < KL / 8; ++r) {
            const uint4 h4 = *(const uint4*)(hs_h + 8 * r);   // broadcast
            const uint4 pa = lw[r][j0];
            const uint4 pb = lw[r][j1];
            a0 = dot2(h4.x, pa.x, a0); a1 = dot2(h4.y, pa.y, a1);
            a0 = dot2(h4.z, pa.z, a0); a1 = dot2(h4.w, pa.w, a1);
            b0 = dot2(h4.x, pb.x, b0); b1 = dot2(h4.y, pb.y, b1);
            b0 = dot2(h4.z, pb.z, b0); b1 = dot2(h4.w, pb.w, b1);
        }

        // k = KL..255: register-resident weights
#pragma unroll
        for (int m = 0; m < NQ / 4; ++m) {
            const uint4 h4 = *(const uint4*)(hs_h + KL + 8 * m);  // broadcast
            a0 = dot2(h4.x, wa[4 * m + 0], a0);
            a1 = dot2(h4.y, wa[4 * m + 1], a1);
            a0 = dot2(h4.z, wa[4 * m + 2], a0);
            a1 = dot2(h4.w, wa[4 * m + 3], a1);
            b0 = dot2(h4.x, wb[4 * m + 0], b0);
            b1 = dot2(h4.y, wb[4 * m + 1], b1);
            b0 = dot2(h4.z, wb[4 * m + 2], b0);
            b1 = dot2(h4.w, wb[4 * m + 3], b1);
        }

        zs[j0] = zx0 + a0 + a1;
        zs[j1] = zx1 + b0 + b1;
        __syncthreads();                            // zs complete

        if (tid < NH) {                             // waves 0-3 (wave-uniform)
            const float iv = zs[tid];
            const float fv = zs[NH + tid];
            const float gv = zs[2 * NH + tid];
            const float ov = zs[3 * NH + tid];
            c = sigf(fv) * c + sigf(iv) * tanh_fast(gv);
            hlast = sigf(ov) * tanh_fast(c);
            hs_h[tid] = (_Float16)hlast;
        }
        __syncthreads();                            // new h visible
    }

    if (tid < NH) out[(size_t)b * NH + tid] = hlast;
}

// ---------------------------------------------------------------------------
// Fallback recurrence (streams weights; used only if ws can't hold ZX)
__global__ __launch_bounds__(512) void rec_fallback(
    const float* __restrict__ X,
    const float* __restrict__ Wi,
    const float* __restrict__ Wh,
    const float* __restrict__ bias,
    const int* __restrict__ lengths,
    float* __restrict__ out)
{
    __shared__ float hs[NH];
    __shared__ float zs[NG];
    __shared__ float xs[ND];

    const int b   = blockIdx.x;
    const int tid = threadIdx.x;
    const int c0  = tid * 2;

    const int len   = lengths[b];
    const int steps = (len < 1) ? 1 : len;

    float c_state = 0.0f;
    if (tid < NH) hs[tid] = 0.0f;
    const float b0 = bias[c0], b1 = bias[c0 + 1];
    __syncthreads();

    for (int t = 0; t < steps; ++t) {
        float a0 = b0, a1 = b1;
        if (tid < ND) xs[tid] = X[((size_t)b * NT + t) * ND + tid];
        __syncthreads();
#pragma unroll 2
        for (int k = 0; k < ND; k += 4) {
            const float4 xv = *(const float4*)(xs + k);
            const float2 w0 = *(const float2*)(Wi + (size_t)(k + 0) * NG + c0);
            const float2 w1 = *(const float2*)(Wi + (size_t)(k + 1) * NG + c0);
            const float2 w2 = *(const float2*)(Wi + (size_t)(k + 2) * NG + c0);
            const float2 w3 = *(const float2*)(Wi + (size_t)(k + 3) * NG + c0);
            a0 = fmaf(xv.x, w0.x, a0); a1 = fmaf(xv.x, w0.y, a1);
            a0 = fmaf(xv.y, w1.x, a0); a1 = fmaf(xv.y, w1.y, a1);
            a0 = fmaf(xv.z, w2.x, a0); a1 = fmaf(xv.z, w2.y, a1);
            a0 = fmaf(xv.w, w3.x, a0); a1 = fmaf(xv.w, w3.y, a1);
        }
#pragma unroll 2
        for (int k = 0; k < NH; k += 4) {
            const float4 hv = *(const float4*)(hs + k);
            const float2 w0 = *(const float2*)(Wh + (size_t)(k + 0) * NG + c0);
            const float2 w1 = *(const float2*)(Wh + (size_t)(k + 1) * NG + c0);
            const float2 w2 = *(const float2*)(Wh + (size_t)(k + 2) * NG + c0);
            const float2 w3 = *(const float2*)(Wh + (size_t)(k + 3) * NG + c0);
            a0 = fmaf(hv.x, w0.x, a0); a1 = fmaf(hv.x, w0.y, a1);
            a0 = fmaf(hv.y, w1.x, a0); a1 = fmaf(hv.y, w1.y, a1);
            a0 = fmaf(hv.z, w2.x, a0); a1 = fmaf(hv.z, w2.y, a1);
            a0 = fmaf(hv.w, w3.x, a0); a1 = fmaf(hv.w, w3.y, a1);
        }

        float2 zo2; zo2.x = a0; zo2.y = a1;
        *(float2*)(zs + c0) = zo2;
        __syncthreads();

        if (tid < NH) {
            const float iv = zs[tid];
            const float fv = zs[NH + tid];
            const float gv = zs[2 * NH + tid];
            const float ov = zs[3 * NH + tid];
            c_state = sigf(fv) * c_state + sigf(iv) * tanh_fast(gv);
            hs[tid] = sigf(ov) * tanh_fast(c_state);
        }
        __syncthreads();
    }

    if (tid < NH) out[(size_t)b * NH + tid] = hs[tid];
}

extern "C" void kernel_launch(void* const* d_in, const int* in_sizes, int n_in,
                              void* d_out, int out_size, void* d_ws, size_t ws_size,
                              hipStream_t stream) {
    const float* X       = (const float*)d_in[0];
    const int*   lengths = (const int*)d_in[1];
    const float* Wi      = (const float*)d_in[2];
    const float* Wh      = (const float*)d_in[3];
    const float* bias    = (const float*)d_in[4];
    float* out = (float*)d_out;

    const size_t zx_bytes = (size_t)NB * NT * NG * sizeof(float);  // 256 MB
    float* ZX = (float*)d_ws;

    if (ws_size >= zx_bytes) {
        zx_mfma<<<dim3((NB * NT) / 64, NG / 256), dim3(256), 0, stream>>>(X, Wi, bias, ZX);
        rec_pers<<<dim3(NB), dim3(TPB), 0, stream>>>(ZX, Wh, lengths, out);
    } else {
        rec_fallback<<<dim3(NB), dim3(512), 0, stream>>>(X, Wi, Wh, bias, lengths, out);
    }
}